// Round 1
// baseline (18325.119 us; speedup 1.0000x reference)
//
#include <hip/hip_runtime.h>
#include <hip/hip_bf16.h>
#include <math.h>

// Problem shapes (compile-time constants from the reference)
#define BATCH 4096
#define LATENT_DIM 20480
#define HIDDEN 4096
#define COND_DIM 64
#define TIME_DIM 64
#define IN_DIM (LATENT_DIM + COND_DIM + TIME_DIM)  // 20608
#define TAIL_DIM (COND_DIM + TIME_DIM)             // 128

// ---------------------------------------------------------------------------
// Kernel 1: time-feature MLP + digit embedding -> tail[B][128]
//   tail[b][0:64]   = emb_table[digits[b]]
//   tail[b][64:128] = t_embed(b)
// blockDim = (64, 4): 64 threads per batch row, 4 rows per block.
// ---------------------------------------------------------------------------
__global__ __launch_bounds__(256) void tail_kernel(
    const int* __restrict__ digits, const int* __restrict__ timesteps,
    const int* __restrict__ num_steps_p,
    const float* __restrict__ emb,   // [3,64]
    const float* __restrict__ tw0,   // [64,4]
    const float* __restrict__ tb0,   // [64]
    const float* __restrict__ tw1,   // [64,64]
    const float* __restrict__ tb1,   // [64]
    float* __restrict__ tail)        // [B,128]
{
    const int j = threadIdx.x;          // 0..63
    const int row = threadIdx.y;        // 0..3
    const int b = blockIdx.x * 4 + row;
    __shared__ float hsh[4][64];

    const int ns = num_steps_p[0];
    const float denom = (float)((ns - 1) > 1 ? (ns - 1) : 1);
    const float t = (float)timesteps[b] / denom;
    const float pi = 3.14159265358979323846f;
    const float f0 = t, f1 = t * t, f2 = sinf(pi * t), f3 = cosf(pi * t);

    float h = f0 * tw0[j * 4 + 0] + f1 * tw0[j * 4 + 1] +
              f2 * tw0[j * 4 + 2] + f3 * tw0[j * 4 + 3] + tb0[j];
    h = fmaxf(h, 0.0f);
    hsh[row][j] = h;
    __syncthreads();

    float acc = tb1[j];
    #pragma unroll 8
    for (int i = 0; i < 64; i++)
        acc = fmaf(hsh[row][i], tw1[j * 64 + i], acc);

    const int d = digits[b];
    tail[(size_t)b * TAIL_DIM + j] = emb[d * 64 + j];
    tail[(size_t)b * TAIL_DIM + 64 + j] = acc;
}

// ---------------------------------------------------------------------------
// Kernel 2: fp32 tiled GEMM, C[M,N] = act( A[M,K] * W[N,K]^T + bias[N] )
// A is split: columns [0,Ka) come from A (row stride lda), columns [Ka,K)
// from At (row stride ldt).  Requires Ka % BK == 0, M % BM == 0, N % BN == 0,
// K % BK == 0.
// Block tile 128x128, 256 threads, 8x8 per thread, BK=16.
// ---------------------------------------------------------------------------
#define BM 128
#define BN 128
#define BK 16

template <int RELU>
__global__ __launch_bounds__(256) void gemm_bt(
    const float* __restrict__ A, int lda,
    const float* __restrict__ At, int ldt,
    const float* __restrict__ W,      // [N,K]
    const float* __restrict__ bias,   // [N]
    float* __restrict__ C,            // [M,N]
    int M, int N, int Ka, int K)
{
    __shared__ float As[BK][BM + 4];
    __shared__ float Bs[BK][BN + 4];

    const int tid = threadIdx.x;
    const int m0 = blockIdx.y * BM;
    const int n0 = blockIdx.x * BN;
    const int tx = tid & 15;   // 0..15 -> N direction
    const int ty = tid >> 4;   // 0..15 -> M direction

    float acc[8][8];
    #pragma unroll
    for (int i = 0; i < 8; i++)
        #pragma unroll
        for (int j = 0; j < 8; j++) acc[i][j] = 0.0f;

    for (int k0 = 0; k0 < K; k0 += BK) {
        // --- stage A tile (BM x BK) into As[k][m] (transposed) ---
        #pragma unroll
        for (int it = 0; it < 2; it++) {
            const int idx = tid + it * 256;        // 0..511
            const int r = idx >> 2;                // 0..127
            const int c4 = (idx & 3) * 4;          // 0,4,8,12
            const int k = k0 + c4;
            const float* src;
            if (k < Ka) src = A + (size_t)(m0 + r) * lda + k;
            else        src = At + (size_t)(m0 + r) * ldt + (k - Ka);
            const float4 v = *(const float4*)src;
            As[c4 + 0][r] = v.x;
            As[c4 + 1][r] = v.y;
            As[c4 + 2][r] = v.z;
            As[c4 + 3][r] = v.w;
        }
        // --- stage W tile (BN x BK) into Bs[k][n] (transposed) ---
        #pragma unroll
        for (int it = 0; it < 2; it++) {
            const int idx = tid + it * 256;
            const int r = idx >> 2;
            const int c4 = (idx & 3) * 4;
            const float4 v = *(const float4*)(W + (size_t)(n0 + r) * K + k0 + c4);
            Bs[c4 + 0][r] = v.x;
            Bs[c4 + 1][r] = v.y;
            Bs[c4 + 2][r] = v.z;
            Bs[c4 + 3][r] = v.w;
        }
        __syncthreads();

        #pragma unroll
        for (int kk = 0; kk < BK; kk++) {
            float a[8], b[8];
            #pragma unroll
            for (int i = 0; i < 8; i++) a[i] = As[kk][ty * 8 + i];
            #pragma unroll
            for (int j = 0; j < 8; j++) b[j] = Bs[kk][tx * 8 + j];
            #pragma unroll
            for (int i = 0; i < 8; i++)
                #pragma unroll
                for (int j = 0; j < 8; j++)
                    acc[i][j] = fmaf(a[i], b[j], acc[i][j]);
        }
        __syncthreads();
    }

    // --- epilogue: bias (+ReLU), vectorized float4 stores ---
    #pragma unroll
    for (int i = 0; i < 8; i++) {
        const int m = m0 + ty * 8 + i;
        const int n = n0 + tx * 8;
        float4 o0, o1;
        float* po = (float*)&o0;
        #pragma unroll
        for (int j = 0; j < 8; j++) {
            float v = acc[i][j] + bias[n + j];
            if (RELU) v = fmaxf(v, 0.0f);
            if (j < 4) ((float*)&o0)[j] = v;
            else       ((float*)&o1)[j - 4] = v;
        }
        (void)po;
        *(float4*)(C + (size_t)m * N + n) = o0;
        *(float4*)(C + (size_t)m * N + n + 4) = o1;
    }
}

// ---------------------------------------------------------------------------
// Launch
// ---------------------------------------------------------------------------
extern "C" void kernel_launch(void* const* d_in, const int* in_sizes, int n_in,
                              void* d_out, int out_size, void* d_ws, size_t ws_size,
                              hipStream_t stream)
{
    const float* noisy  = (const float*)d_in[0];   // [B, 20480]
    const int*   digits = (const int*)d_in[1];     // [B]
    const int*   tsteps = (const int*)d_in[2];     // [B]
    const int*   nsteps = (const int*)d_in[3];     // [1]
    const float* emb    = (const float*)d_in[4];   // [3,64]
    const float* tw0    = (const float*)d_in[5];   // [64,4]
    const float* tb0    = (const float*)d_in[6];   // [64]
    const float* tw1    = (const float*)d_in[7];   // [64,64]
    const float* tb1    = (const float*)d_in[8];   // [64]
    const float* nw0    = (const float*)d_in[9];   // [4096, 20608]
    const float* nb0    = (const float*)d_in[10];  // [4096]
    const float* nw1    = (const float*)d_in[11];  // [4096, 4096]
    const float* nb1    = (const float*)d_in[12];  // [4096]
    const float* nw2    = (const float*)d_in[13];  // [20480, 4096]
    const float* nb2    = (const float*)d_in[14];  // [20480]
    float* out = (float*)d_out;                    // [B, 20480]

    // workspace layout (floats): tail[B*128] | a0[B*4096] | a1[B*4096]
    float* tail = (float*)d_ws;
    float* a0   = tail + (size_t)BATCH * TAIL_DIM;
    float* a1   = a0 + (size_t)BATCH * HIDDEN;

    // 1) time MLP + embedding -> tail
    tail_kernel<<<BATCH / 4, dim3(64, 4), 0, stream>>>(
        digits, tsteps, nsteps, emb, tw0, tb0, tw1, tb1, tail);

    // 2) a0 = relu(net_in @ nw0^T + nb0)   M=4096 N=4096 K=20608 (split 20480)
    gemm_bt<1><<<dim3(HIDDEN / BN, BATCH / BM), 256, 0, stream>>>(
        noisy, LATENT_DIM, tail, TAIL_DIM, nw0, nb0, a0,
        BATCH, HIDDEN, LATENT_DIM, IN_DIM);

    // 3) a1 = relu(a0 @ nw1^T + nb1)       M=4096 N=4096 K=4096
    gemm_bt<1><<<dim3(HIDDEN / BN, BATCH / BM), 256, 0, stream>>>(
        a0, HIDDEN, a0, HIDDEN, nw1, nb1, a1,
        BATCH, HIDDEN, HIDDEN, HIDDEN);

    // 4) out = a1 @ nw2^T + nb2            M=4096 N=20480 K=4096
    gemm_bt<0><<<dim3(LATENT_DIM / BN, BATCH / BM), 256, 0, stream>>>(
        a1, HIDDEN, a1, HIDDEN, nw2, nb2, out,
        BATCH, LATENT_DIM, HIDDEN, HIDDEN);
}